// Round 2
// baseline (9361.498 us; speedup 1.0000x reference)
//
#include <hip/hip_runtime.h>
#include <hip/hip_bf16.h>
#include <math.h>

#define BB 64
#define SS 196
#define DD 768
#define EE 4
#define KKE 2
#define THH 196
#define MHH 3072
#define N1 (BB*SS*DD)

__device__ __forceinline__ float gelu_exact(float x){
    return 0.5f * x * (1.0f + erff(x * 0.70710678118654752f));
}

// ---------------- LN over last dim (768 = 3*256) ----------------
__global__ __launch_bounds__(256) void ln_kernel(const float* __restrict__ x,
                                                 const float* __restrict__ g,
                                                 const float* __restrict__ b,
                                                 float* __restrict__ out){
    int row = blockIdx.x;
    int tid = threadIdx.x;
    const float* xr = x + (size_t)row * DD;
    float v0 = xr[tid], v1 = xr[tid+256], v2 = xr[tid+512];
    float s = v0+v1+v2, ss = v0*v0+v1*v1+v2*v2;
    __shared__ float sh[10];
    int lane = tid & 63, wid = tid >> 6;
    #pragma unroll
    for (int o=32;o>0;o>>=1){ s += __shfl_down(s,o); ss += __shfl_down(ss,o); }
    if (lane==0){ sh[wid]=s; sh[4+wid]=ss; }
    __syncthreads();
    if (tid==0){
        float S1=sh[0]+sh[1]+sh[2]+sh[3], S2=sh[4]+sh[5]+sh[6]+sh[7];
        float mu = S1/DD; float var = S2/DD - mu*mu;
        sh[8]=mu; sh[9]=rsqrtf(var + 1e-6f);
    }
    __syncthreads();
    float mu=sh[8], rs=sh[9];
    float* orow = out + (size_t)row*DD;
    orow[tid]     = (v0-mu)*rs*g[tid]     + b[tid];
    orow[tid+256] = (v1-mu)*rs*g[tid+256] + b[tid+256];
    orow[tid+512] = (v2-mu)*rs*g[tid+512] + b[tid+512];
}

// ---------------- router: mean over S, @Wg, softmax, top-2 ----------------
__global__ __launch_bounds__(256) void router_kernel(const float* __restrict__ normed,
                                                     const float* __restrict__ Wg,
                                                     const float* __restrict__ bg,
                                                     float* __restrict__ combine,
                                                     float* __restrict__ probs,
                                                     int* __restrict__ topi,
                                                     float* __restrict__ topw){
    int b = blockIdx.x, tid = threadIdx.x;
    float pl[EE] = {0.f,0.f,0.f,0.f};
    for (int i = 0; i < 3; ++i){
        int d = tid + i*256;
        const float* base = normed + (size_t)b*SS*DD + d;
        float acc = 0.f;
        for (int s = 0; s < SS; ++s) acc += base[(size_t)s*DD];
        float mp = acc / (float)SS;
        #pragma unroll
        for (int e=0;e<EE;++e) pl[e] += mp * Wg[d*EE + e];
    }
    __shared__ float sh[4][EE];
    int lane = tid&63, wid = tid>>6;
    #pragma unroll
    for (int e=0;e<EE;++e){
        #pragma unroll
        for (int o=32;o>0;o>>=1) pl[e] += __shfl_down(pl[e], o);
    }
    if (lane==0){ for(int e=0;e<EE;++e) sh[wid][e]=pl[e]; }
    __syncthreads();
    if (tid==0){
        float lg[EE];
        for (int e=0;e<EE;++e) lg[e] = sh[0][e]+sh[1][e]+sh[2][e]+sh[3][e] + bg[e];
        float mx = lg[0];
        for (int e=1;e<EE;++e) mx = fmaxf(mx, lg[e]);
        float p[EE]; float sum=0.f;
        for (int e=0;e<EE;++e){ p[e]=expf(lg[e]-mx); sum+=p[e]; }
        for (int e=0;e<EE;++e) p[e] /= sum;
        int i0=0; for (int e=1;e<EE;++e) if (p[e]>p[i0]) i0=e;
        int i1=-1;
        for (int e=0;e<EE;++e){ if (e==i0) continue; if (i1<0 || p[e]>p[i1]) i1=e; }
        float v0=p[i0], v1=p[i1], rsum=v0+v1;
        float w0=v0/rsum, w1=v1/rsum;
        for (int e=0;e<EE;++e){ probs[b*EE+e]=p[e]; combine[b*EE+e]=0.f; }
        combine[b*EE+i0]=w0; combine[b*EE+i1]=w1;
        topi[b*KKE]=i0; topi[b*KKE+1]=i1;
        topw[b*KKE]=w0; topw[b*KKE+1]=w1;
    }
}

// ---------------- aux loss ----------------
__global__ __launch_bounds__(256) void aux_kernel(const float* __restrict__ combine,
                                                  const float* __restrict__ probs,
                                                  float* __restrict__ aux_out){
    int tid = threadIdx.x; int e = tid>>6, b = tid&63;
    float m = combine[b*EE+e] > 0.f ? 1.f : 0.f;
    float p = probs[b*EE+e];
    #pragma unroll
    for (int o=32;o>0;o>>=1){ m += __shfl_down(m,o); p += __shfl_down(p,o); }
    __shared__ float sh[EE];
    if ((tid&63)==0) sh[e] = (m/(float)BB)*(p/(float)BB);
    __syncthreads();
    if (tid==0) aux_out[0] = (float)EE * (sh[0]+sh[1]+sh[2]+sh[3]);
}

// ---------------- token mixing: per (b,d), both top-2 experts ----------------
__global__ __launch_bounds__(256) void tokenmix_kernel(const float* __restrict__ normed,
                                                       const float* __restrict__ x,
                                                       const float* __restrict__ W1,
                                                       const float* __restrict__ b1,
                                                       const float* __restrict__ W2,
                                                       const float* __restrict__ b2,
                                                       const int* __restrict__ topi,
                                                       const float* __restrict__ topw,
                                                       float* __restrict__ x1){
    int d = blockIdx.x, b = blockIdx.y, tid = threadIdx.x;
    __shared__ float xcol[SS];
    __shared__ float H[THH];
    for (int i = tid; i < SS; i += 256)
        xcol[i] = normed[(size_t)b*SS*DD + (size_t)i*DD + d];
    float macc = 0.f;
    #pragma unroll
    for (int k=0;k<KKE;++k){
        int e = topi[b*KKE+k];
        float w = topw[b*KKE+k];
        __syncthreads();
        if (tid < THH){
            float acc = b1[e*THH + tid];
            const float* w1p = W1 + (size_t)e*SS*THH + tid;
            #pragma unroll 4
            for (int s=0;s<SS;++s) acc += xcol[s]*w1p[(size_t)s*THH];
            H[tid] = gelu_exact(acc);
        }
        __syncthreads();
        if (tid < SS){
            float o = b2[e*SS + tid];
            const float* w2p = W2 + (size_t)e*THH*SS + tid;
            #pragma unroll 4
            for (int h=0;h<THH;++h) o += H[h]*w2p[(size_t)h*SS];
            macc += w*o;
        }
    }
    if (tid < SS){
        size_t idx = (size_t)b*SS*DD + (size_t)tid*DD + d;
        x1[idx] = x[idx] + macc;
    }
}

// ---------------- fused channel MLP: out(io=x1) += gelu(n2@Wm1+bm1)@Wm2 + bm2 ----------------
__global__ __launch_bounds__(256) void mlp_kernel(const float* __restrict__ n2,
                                                  const float* __restrict__ Wm1,
                                                  const float* __restrict__ bm1,
                                                  const float* __restrict__ Wm2,
                                                  const float* __restrict__ bm2,
                                                  float* __restrict__ io){
    int tid = threadIdx.x;
    int m0 = blockIdx.x * 16;
    __shared__ float n2s[16][DD];
    __shared__ float hhs[16][64];
    for (int i = tid; i < 16*DD; i += 256){
        int r = i / DD, c2 = i % DD;
        n2s[r][c2] = n2[(size_t)(m0+r)*DD + c2];
    }
    float acc[16][3];
    #pragma unroll
    for (int r=0;r<16;++r){ acc[r][0]=0.f; acc[r][1]=0.f; acc[r][2]=0.f; }
    int q = tid >> 6, c = tid & 63;
    __syncthreads();
    for (int ht = 0; ht < MHH/64; ++ht){
        int h0 = ht*64;
        // phase A: hh tile [16][64]
        float a0=0.f,a1=0.f,a2=0.f,a3=0.f;
        const float* wp = Wm1 + (size_t)h0 + c;
        #pragma unroll 4
        for (int kk=0; kk<DD; ++kk){
            float wv = wp[(size_t)kk*MHH];
            a0 += n2s[q][kk]*wv;
            a1 += n2s[q+4][kk]*wv;
            a2 += n2s[q+8][kk]*wv;
            a3 += n2s[q+12][kk]*wv;
        }
        float bv = bm1[h0 + c];
        hhs[q][c]    = gelu_exact(a0+bv);
        hhs[q+4][c]  = gelu_exact(a1+bv);
        hhs[q+8][c]  = gelu_exact(a2+bv);
        hhs[q+12][c] = gelu_exact(a3+bv);
        __syncthreads();
        // phase B: acc += hh @ Wm2[h0:h0+64, :]
        const float* w2p = Wm2 + (size_t)h0*DD + tid;
        #pragma unroll 2
        for (int j=0;j<64;++j){
            float w0  = w2p[(size_t)j*DD];
            float w1  = w2p[(size_t)j*DD + 256];
            float w2v = w2p[(size_t)j*DD + 512];
            #pragma unroll
            for (int r=0;r<16;++r){
                float hv = hhs[r][j];
                acc[r][0] += hv*w0; acc[r][1] += hv*w1; acc[r][2] += hv*w2v;
            }
        }
        __syncthreads();
    }
    float b0 = bm2[tid], b1v = bm2[tid+256], b2v = bm2[tid+512];
    #pragma unroll
    for (int r=0;r<16;++r){
        size_t base = (size_t)(m0+r)*DD;
        io[base+tid]     += acc[r][0] + b0;
        io[base+tid+256] += acc[r][1] + b1v;
        io[base+tid+512] += acc[r][2] + b2v;
    }
}

extern "C" void kernel_launch(void* const* d_in, const int* in_sizes, int n_in,
                              void* d_out, int out_size, void* d_ws, size_t ws_size,
                              hipStream_t stream) {
    const float* x    = (const float*)d_in[0];
    const float* g1   = (const float*)d_in[1];
    const float* be1  = (const float*)d_in[2];
    const float* Wg   = (const float*)d_in[3];
    const float* bg   = (const float*)d_in[4];
    const float* W1   = (const float*)d_in[5];
    const float* b1e  = (const float*)d_in[6];
    const float* W2   = (const float*)d_in[7];
    const float* b2e  = (const float*)d_in[8];
    const float* g2   = (const float*)d_in[9];
    const float* be2  = (const float*)d_in[10];
    const float* Wm1  = (const float*)d_in[11];
    const float* bm1  = (const float*)d_in[12];
    const float* Wm2  = (const float*)d_in[13];
    const float* bm2  = (const float*)d_in[14];

    float* out = (float*)d_out;
    float* wsf = (float*)d_ws;
    float* normed  = wsf;                 // N1 floats; reused as n2 after token mixing
    float* combine = wsf + (size_t)N1;    // 256
    float* probs   = combine + BB*EE;     // 256
    float* topw    = probs + BB*EE;       // 128
    int*   topi    = (int*)(topw + BB*KKE); // 128 ints

    // 1) LN1 -> normed
    ln_kernel<<<BB*SS, 256, 0, stream>>>(x, g1, be1, normed);
    // 2) router
    router_kernel<<<BB, 256, 0, stream>>>(normed, Wg, bg, combine, probs, topi, topw);
    // 3) aux loss -> out[N1]
    aux_kernel<<<1, 256, 0, stream>>>(combine, probs, out + N1);
    // 4) token mixing + residual -> x1 in d_out
    tokenmix_kernel<<<dim3(DD, BB), 256, 0, stream>>>(normed, x, W1, b1e, W2, b2e,
                                                      topi, topw, out);
    // 5) LN2(x1) -> n2 (reuse normed buffer)
    ln_kernel<<<BB*SS, 256, 0, stream>>>(out, g2, be2, normed);
    // 6) fused MLP + residual (in-place on d_out which holds x1)
    mlp_kernel<<<(BB*SS)/16, 256, 0, stream>>>(normed, Wm1, bm1, Wm2, bm2, out);
}

// Round 6
// 2864.252 us; speedup vs baseline: 3.2684x; 3.2684x over previous
//
#include <hip/hip_runtime.h>
#include <hip/hip_bf16.h>
#include <math.h>

#define BB 64
#define SS 196
#define DD 768
#define EE 4
#define KKE 2
#define THH 196
#define MHH 3072
#define N1 (BB*SS*DD)

typedef __bf16 bf16x8 __attribute__((ext_vector_type(8)));
typedef float f32x4 __attribute__((ext_vector_type(4)));

__device__ __forceinline__ float gelu_exact(float x){
    return 0.5f * x * (1.0f + erff(x * 0.70710678118654752f));
}

// ---------------- LN over last dim -> bf16 out, save mu/rsig ----------------
__global__ __launch_bounds__(256) void ln_bf16_kernel(const float* __restrict__ x,
                                                      const float* __restrict__ g,
                                                      const float* __restrict__ b,
                                                      __hip_bfloat16* __restrict__ out,
                                                      float* __restrict__ muo,
                                                      float* __restrict__ rso){
    int row = blockIdx.x;
    int tid = threadIdx.x;
    const float* xr = x + (size_t)row * DD;
    float v0 = xr[tid], v1 = xr[tid+256], v2 = xr[tid+512];
    float s = v0+v1+v2, ss = v0*v0+v1*v1+v2*v2;
    __shared__ float sh[10];
    int lane = tid & 63, wid = tid >> 6;
    #pragma unroll
    for (int o=32;o>0;o>>=1){ s += __shfl_down(s,o); ss += __shfl_down(ss,o); }
    if (lane==0){ sh[wid]=s; sh[4+wid]=ss; }
    __syncthreads();
    if (tid==0){
        float S1=sh[0]+sh[1]+sh[2]+sh[3], S2=sh[4]+sh[5]+sh[6]+sh[7];
        float mu = S1/DD; float var = S2/DD - mu*mu;
        float rs = rsqrtf(var + 1e-6f);
        sh[8]=mu; sh[9]=rs;
        muo[row]=mu; rso[row]=rs;
    }
    __syncthreads();
    float mu=sh[8], rs=sh[9];
    __hip_bfloat16* orow = out + (size_t)row*DD;
    orow[tid]     = __float2bfloat16((v0-mu)*rs*g[tid]     + b[tid]);
    orow[tid+256] = __float2bfloat16((v1-mu)*rs*g[tid+256] + b[tid+256]);
    orow[tid+512] = __float2bfloat16((v2-mu)*rs*g[tid+512] + b[tid+512]);
}

// ---------------- fp32 transpose -> bf16: dst[c][r] = src[r][c] ----------------
__global__ __launch_bounds__(256) void transpose_bf16_kernel(const float* __restrict__ src,
                                                             __hip_bfloat16* __restrict__ dst,
                                                             int R, int C){
    __shared__ float t[32][33];
    int c0 = blockIdx.x*32, r0 = blockIdx.y*32;
    int tx = threadIdx.x & 31, ty = threadIdx.x >> 5;
    #pragma unroll
    for (int rr = ty; rr < 32; rr += 8)
        t[rr][tx] = src[(size_t)(r0+rr)*C + c0 + tx];
    __syncthreads();
    #pragma unroll
    for (int cc = ty; cc < 32; cc += 8)
        dst[(size_t)(c0+cc)*R + r0 + tx] = __float2bfloat16(t[tx][cc]);
}

// ---------------- router: exact fp32 logits from x + per-row stats ----------------
__global__ __launch_bounds__(256) void router2_kernel(const float* __restrict__ x,
                                                      const float* __restrict__ mu,
                                                      const float* __restrict__ rsig,
                                                      const float* __restrict__ g1,
                                                      const float* __restrict__ b1,
                                                      const float* __restrict__ Wg,
                                                      const float* __restrict__ bg,
                                                      float* __restrict__ combine,
                                                      float* __restrict__ probs,
                                                      int* __restrict__ topi,
                                                      float* __restrict__ topw){
    int b = blockIdx.x, tid = threadIdx.x;
    __shared__ float smu[SS], srs[SS];
    for (int s = tid; s < SS; s += 256){ smu[s]=mu[b*SS+s]; srs[s]=rsig[b*SS+s]; }
    __syncthreads();
    float pl[EE] = {0.f,0.f,0.f,0.f};
    for (int i = 0; i < 3; ++i){
        int d = tid + i*256;
        const float* base = x + (size_t)b*SS*DD + d;
        float acc = 0.f;
        for (int s = 0; s < SS; ++s) acc += (base[(size_t)s*DD]-smu[s])*srs[s];
        float mp = g1[d]*(acc/(float)SS) + b1[d];
        #pragma unroll
        for (int e=0;e<EE;++e) pl[e] += mp * Wg[d*EE + e];
    }
    __shared__ float sh[4][EE];
    int lane = tid&63, wid = tid>>6;
    #pragma unroll
    for (int e=0;e<EE;++e){
        #pragma unroll
        for (int o=32;o>0;o>>=1) pl[e] += __shfl_down(pl[e], o);
    }
    if (lane==0){ for(int e=0;e<EE;++e) sh[wid][e]=pl[e]; }
    __syncthreads();
    if (tid==0){
        float lg[EE];
        for (int e=0;e<EE;++e) lg[e] = sh[0][e]+sh[1][e]+sh[2][e]+sh[3][e] + bg[e];
        float mx = lg[0];
        for (int e=1;e<EE;++e) mx = fmaxf(mx, lg[e]);
        float p[EE]; float sum=0.f;
        for (int e=0;e<EE;++e){ p[e]=expf(lg[e]-mx); sum+=p[e]; }
        for (int e=0;e<EE;++e) p[e] /= sum;
        int i0=0; for (int e=1;e<EE;++e) if (p[e]>p[i0]) i0=e;
        int i1=-1;
        for (int e=0;e<EE;++e){ if (e==i0) continue; if (i1<0 || p[e]>p[i1]) i1=e; }
        float v0=p[i0], v1=p[i1], rsum=v0+v1;
        float w0=v0/rsum, w1=v1/rsum;
        for (int e=0;e<EE;++e){ probs[b*EE+e]=p[e]; combine[b*EE+e]=0.f; }
        combine[b*EE+i0]=w0; combine[b*EE+i1]=w1;
        topi[b*KKE]=i0; topi[b*KKE+1]=i1;
        topw[b*KKE]=w0; topw[b*KKE+1]=w1;
    }
}

// ---------------- aux loss ----------------
__global__ __launch_bounds__(256) void aux_kernel(const float* __restrict__ combine,
                                                  const float* __restrict__ probs,
                                                  float* __restrict__ aux_out){
    int tid = threadIdx.x; int e = tid>>6, b = tid&63;
    float m = combine[b*EE+e] > 0.f ? 1.f : 0.f;
    float p = probs[b*EE+e];
    #pragma unroll
    for (int o=32;o>0;o>>=1){ m += __shfl_down(m,o); p += __shfl_down(p,o); }
    __shared__ float sh[EE];
    if ((tid&63)==0) sh[e] = (m/(float)BB)*(p/(float)BB);
    __syncthreads();
    if (tid==0) aux_out[0] = (float)EE * (sh[0]+sh[1]+sh[2]+sh[3]);
}

// ---------------- token mixing: per (b,d), both top-2 experts ----------------
__global__ __launch_bounds__(256) void tokenmix_kernel(const __hip_bfloat16* __restrict__ normed,
                                                       const float* __restrict__ x,
                                                       const float* __restrict__ W1,
                                                       const float* __restrict__ b1,
                                                       const float* __restrict__ W2,
                                                       const float* __restrict__ b2,
                                                       const int* __restrict__ topi,
                                                       const float* __restrict__ topw,
                                                       float* __restrict__ x1){
    int d = blockIdx.x, b = blockIdx.y, tid = threadIdx.x;
    __shared__ float xcol[SS];
    __shared__ float H[THH];
    for (int i = tid; i < SS; i += 256)
        xcol[i] = __bfloat162float(normed[(size_t)b*SS*DD + (size_t)i*DD + d]);
    float macc = 0.f;
    #pragma unroll
    for (int k=0;k<KKE;++k){
        int e = topi[b*KKE+k];
        float w = topw[b*KKE+k];
        __syncthreads();
        if (tid < THH){
            float acc = b1[e*THH + tid];
            const float* w1p = W1 + (size_t)e*SS*THH + tid;
            #pragma unroll 4
            for (int s=0;s<SS;++s) acc += xcol[s]*w1p[(size_t)s*THH];
            H[tid] = gelu_exact(acc);
        }
        __syncthreads();
        if (tid < SS){
            float o = b2[e*SS + tid];
            const float* w2p = W2 + (size_t)e*THH*SS + tid;
            #pragma unroll 4
            for (int h=0;h<THH;++h) o += H[h]*w2p[(size_t)h*SS];
            macc += w*o;
        }
    }
    if (tid < SS){
        size_t idx = (size_t)b*SS*DD + (size_t)tid*DD + d;
        x1[idx] = x[idx] + macc;
    }
}

// ---------------- fused channel MLP via MFMA ----------------
// io += gelu(n2b @ Wm1 + bm1) @ Wm2 + bm2, using bf16 MFMA 16x16x32.
// Block: 512 thr (8 waves, 2M x 4N), M-tile 32 rows, hidden chunk 64.
// A-frags: n2b[row][k] contiguous 16B. B-frags: pre-transposed w1t[n][k], w2t[n][k].
// H tile relayed through 4KB XOR-swizzled LDS.
__global__ __launch_bounds__(512, 4) void mlp_mfma_kernel(
    const __hip_bfloat16* __restrict__ n2b,   // [12544][768]
    const __hip_bfloat16* __restrict__ w1t,   // [3072][768]
    const float* __restrict__ bm1,            // [3072]
    const __hip_bfloat16* __restrict__ w2t,   // [768][3072]
    const float* __restrict__ bm2,            // [768]
    float* __restrict__ io)                   // [12544][768], +=
{
    __shared__ __align__(16) __hip_bfloat16 Ht[32*64];
    int tid = threadIdx.x;
    int wid = tid >> 6, lane = tid & 63;
    int wm = wid >> 2, wn = wid & 3;
    int l15 = lane & 15, l4 = lane >> 4;
    int m0 = blockIdx.x * 32;

    f32x4 acc[12];
    #pragma unroll
    for (int f=0; f<12; ++f) acc[f] = (f32x4){0.f,0.f,0.f,0.f};

    const __hip_bfloat16* aptr = n2b + (size_t)(m0 + wm*16 + l15)*DD + l4*8;

    for (int hc = 0; hc < MHH; hc += 64) {
        // ---- GEMM1: Hfrag(16x16) = A(m) x w1t(hc+wn*16), K=768 ----
        f32x4 h = (f32x4){0.f,0.f,0.f,0.f};
        const __hip_bfloat16* bptr = w1t + (size_t)(hc + wn*16 + l15)*DD + l4*8;
        #pragma unroll 4
        for (int ks = 0; ks < DD; ks += 32) {
            bf16x8 a = *reinterpret_cast<const bf16x8*>(aptr + ks);
            bf16x8 bb = *reinterpret_cast<const bf16x8*>(bptr + ks);
            h = __builtin_amdgcn_mfma_f32_16x16x32_bf16(a, bb, h, 0, 0, 0);
        }
        float bv = bm1[hc + wn*16 + l15];
        __syncthreads();   // previous chunk's Ht reads complete
        {
            int col = wn*16 + l15;            // 0..63 within chunk
            int chunk = col >> 3, inner = col & 7;
            #pragma unroll
            for (int r=0; r<4; ++r) {
                int row = wm*16 + l4*4 + r;   // 0..31
                float v = gelu_exact(h[r] + bv);
                Ht[row*64 + ((chunk ^ (row&7))<<3) + inner] = __float2bfloat16(v);
            }
        }
        __syncthreads();
        // ---- GEMM2: acc += Ht[32][64] @ w2t-cols, K=64 (2 mfma k-steps) ----
        #pragma unroll
        for (int kk = 0; kk < 2; ++kk) {
            int arow = wm*16 + l15;
            int ach = (kk*32 + l4*8) >> 3;    // 16B chunk index 0..7
            bf16x8 aH = *reinterpret_cast<const bf16x8*>(
                &Ht[arow*64 + ((ach ^ (arow&7))<<3)]);
            const __hip_bfloat16* b2p = w2t + (size_t)(wn*192 + l15)*MHH + hc + kk*32 + l4*8;
            #pragma unroll
            for (int f=0; f<12; ++f) {
                bf16x8 bb = *reinterpret_cast<const bf16x8*>(b2p + (size_t)f*16*MHH);
                acc[f] = __builtin_amdgcn_mfma_f32_16x16x32_bf16(aH, bb, acc[f], 0, 0, 0);
            }
        }
    }
    // ---- epilogue: io[row][col] += acc + bm2 ----
    #pragma unroll
    for (int f=0; f<12; ++f) {
        int col = wn*192 + f*16 + l15;
        float b2v = bm2[col];
        #pragma unroll
        for (int r=0; r<4; ++r) {
            size_t idx = (size_t)(m0 + wm*16 + l4*4 + r)*DD + col;
            io[idx] += acc[f][r] + b2v;
        }
    }
}

extern "C" void kernel_launch(void* const* d_in, const int* in_sizes, int n_in,
                              void* d_out, int out_size, void* d_ws, size_t ws_size,
                              hipStream_t stream) {
    const float* x    = (const float*)d_in[0];
    const float* g1   = (const float*)d_in[1];
    const float* be1  = (const float*)d_in[2];
    const float* Wg   = (const float*)d_in[3];
    const float* bg   = (const float*)d_in[4];
    const float* W1   = (const float*)d_in[5];
    const float* b1e  = (const float*)d_in[6];
    const float* W2   = (const float*)d_in[7];
    const float* b2e  = (const float*)d_in[8];
    const float* g2   = (const float*)d_in[9];
    const float* be2  = (const float*)d_in[10];
    const float* Wm1  = (const float*)d_in[11];
    const float* bm1  = (const float*)d_in[12];
    const float* Wm2  = (const float*)d_in[13];
    const float* bm2  = (const float*)d_in[14];

    float* out = (float*)d_out;

    // ws layout (all 16B aligned), total ~28.8 MB
    char* w = (char*)d_ws;
    __hip_bfloat16* nbf = (__hip_bfloat16*)w;                       // 12544*768 bf16 = 19,267,584 B
    __hip_bfloat16* w1t = (__hip_bfloat16*)(w + 19267584);          // 3072*768 bf16 = 4,718,592 B
    __hip_bfloat16* w2t = (__hip_bfloat16*)(w + 19267584 + 4718592);// 768*3072 bf16 = 4,718,592 B
    float* muv     = (float*)(w + 19267584 + 2*4718592);            // 12544 f32
    float* rsigv   = muv + BB*SS;
    float* combine = rsigv + BB*SS;
    float* probs   = combine + BB*EE;
    float* topw    = probs + BB*EE;
    int*   topi    = (int*)(topw + BB*KKE);

    // 0) one-off weight transposes to bf16 [n][k]
    transpose_bf16_kernel<<<dim3(MHH/32, DD/32), 256, 0, stream>>>(Wm1, w1t, DD, MHH);
    transpose_bf16_kernel<<<dim3(DD/32, MHH/32), 256, 0, stream>>>(Wm2, w2t, MHH, DD);
    // 1) LN1 -> nbf (bf16) + mu/rsig
    ln_bf16_kernel<<<BB*SS, 256, 0, stream>>>(x, g1, be1, nbf, muv, rsigv);
    // 2) router (exact fp32 from x + stats)
    router2_kernel<<<BB, 256, 0, stream>>>(x, muv, rsigv, g1, be1, Wg, bg,
                                           combine, probs, topi, topw);
    // 3) aux loss -> out[N1]
    aux_kernel<<<1, 256, 0, stream>>>(combine, probs, out + N1);
    // 4) token mixing + residual -> x1 in d_out
    tokenmix_kernel<<<dim3(DD, BB), 256, 0, stream>>>(nbf, x, W1, b1e, W2, b2e,
                                                      topi, topw, out);
    // 5) LN2(x1) -> nbf (reuse; tokenmix already consumed it)
    ln_bf16_kernel<<<BB*SS, 256, 0, stream>>>(out, g2, be2, nbf, muv, rsigv);
    // 6) fused MFMA MLP + residual (in-place on d_out which holds x1)
    mlp_mfma_kernel<<<(BB*SS)/32, 512, 0, stream>>>(nbf, w1t, bm1, w2t, bm2, out);
}

// Round 7
// 1148.073 us; speedup vs baseline: 8.1541x; 2.4948x over previous
//
#include <hip/hip_runtime.h>
#include <hip/hip_bf16.h>
#include <math.h>

#define BB 64
#define SS 196
#define DD 768
#define EE 4
#define KKE 2
#define THH 196
#define MHH 3072
#define N1 (BB*SS*DD)
#define MM (BB*SS)

typedef __bf16 bf16x8 __attribute__((ext_vector_type(8)));
typedef float f32x4 __attribute__((ext_vector_type(4)));

__device__ __forceinline__ float gelu_exact(float x){
    return 0.5f * x * (1.0f + erff(x * 0.70710678118654752f));
}

// ---------------- LN over last dim -> bf16 out, save mu/rsig ----------------
__global__ __launch_bounds__(256) void ln_bf16_kernel(const float* __restrict__ x,
                                                      const float* __restrict__ g,
                                                      const float* __restrict__ b,
                                                      __hip_bfloat16* __restrict__ out,
                                                      float* __restrict__ muo,
                                                      float* __restrict__ rso){
    int row = blockIdx.x;
    int tid = threadIdx.x;
    const float* xr = x + (size_t)row * DD;
    float v0 = xr[tid], v1 = xr[tid+256], v2 = xr[tid+512];
    float s = v0+v1+v2, ss = v0*v0+v1*v1+v2*v2;
    __shared__ float sh[10];
    int lane = tid & 63, wid = tid >> 6;
    #pragma unroll
    for (int o=32;o>0;o>>=1){ s += __shfl_down(s,o); ss += __shfl_down(ss,o); }
    if (lane==0){ sh[wid]=s; sh[4+wid]=ss; }
    __syncthreads();
    if (tid==0){
        float S1=sh[0]+sh[1]+sh[2]+sh[3], S2=sh[4]+sh[5]+sh[6]+sh[7];
        float mu = S1/DD; float var = S2/DD - mu*mu;
        float rs = rsqrtf(var + 1e-6f);
        sh[8]=mu; sh[9]=rs;
        muo[row]=mu; rso[row]=rs;
    }
    __syncthreads();
    float mu=sh[8], rs=sh[9];
    __hip_bfloat16* orow = out + (size_t)row*DD;
    orow[tid]     = __float2bfloat16((v0-mu)*rs*g[tid]     + b[tid]);
    orow[tid+256] = __float2bfloat16((v1-mu)*rs*g[tid+256] + b[tid+256]);
    orow[tid+512] = __float2bfloat16((v2-mu)*rs*g[tid+512] + b[tid+512]);
}

// ---------------- fp32 transpose -> bf16: dst[c][r] = src[r][c] ----------------
__global__ __launch_bounds__(256) void transpose_bf16_kernel(const float* __restrict__ src,
                                                             __hip_bfloat16* __restrict__ dst,
                                                             int R, int C){
    __shared__ float t[32][33];
    int c0 = blockIdx.x*32, r0 = blockIdx.y*32;
    int tx = threadIdx.x & 31, ty = threadIdx.x >> 5;
    #pragma unroll
    for (int rr = ty; rr < 32; rr += 8)
        t[rr][tx] = src[(size_t)(r0+rr)*C + c0 + tx];
    __syncthreads();
    #pragma unroll
    for (int cc = ty; cc < 32; cc += 8)
        dst[(size_t)(c0+cc)*R + r0 + tx] = __float2bfloat16(t[tx][cc]);
}

// ---------------- meanvec: mv[b][d] = g1[d]*mean_s((x-mu)*rs) + b1[d], exact fp32 ----------------
__global__ __launch_bounds__(384) void meanvec_kernel(const float* __restrict__ x,
                                                      const float* __restrict__ mu,
                                                      const float* __restrict__ rs,
                                                      const float* __restrict__ g1,
                                                      const float* __restrict__ b1,
                                                      float* __restrict__ mv){
    int b = blockIdx.y, d = blockIdx.x*384 + threadIdx.x;
    __shared__ float smu[SS], srs[SS];
    for (int s=threadIdx.x; s<SS; s+=384){ smu[s]=mu[b*SS+s]; srs[s]=rs[b*SS+s]; }
    __syncthreads();
    const float* base = x + (size_t)b*SS*DD + d;
    float a0=0.f, a1=0.f;
    for (int s=0;s<SS;s+=2){
        a0 += (base[(size_t)s*DD]     - smu[s])  * srs[s];
        a1 += (base[(size_t)(s+1)*DD] - smu[s+1])* srs[s+1];
    }
    mv[(size_t)b*DD + d] = g1[d]*((a0+a1)/(float)SS) + b1[d];
}

// ---------------- logits + softmax + top-2 (one wave per batch) ----------------
__global__ __launch_bounds__(64) void logits_kernel(const float* __restrict__ mv,
                                                    const float* __restrict__ Wg,
                                                    const float* __restrict__ bg,
                                                    float* __restrict__ combine,
                                                    float* __restrict__ probs,
                                                    int* __restrict__ topi,
                                                    float* __restrict__ topw){
    int b = blockIdx.x, lane = threadIdx.x;
    float pl[EE] = {0.f,0.f,0.f,0.f};
    #pragma unroll
    for (int i=0;i<DD/64;++i){
        int d = lane + i*64;
        float m = mv[(size_t)b*DD + d];
        #pragma unroll
        for (int e=0;e<EE;++e) pl[e] += m * Wg[d*EE + e];
    }
    #pragma unroll
    for (int e=0;e<EE;++e){
        #pragma unroll
        for (int o=32;o>0;o>>=1) pl[e] += __shfl_down(pl[e], o);
    }
    if (lane==0){
        float lg[EE];
        for (int e=0;e<EE;++e) lg[e] = pl[e] + bg[e];
        float mx = lg[0];
        for (int e=1;e<EE;++e) mx = fmaxf(mx, lg[e]);
        float p[EE]; float sum=0.f;
        for (int e=0;e<EE;++e){ p[e]=expf(lg[e]-mx); sum+=p[e]; }
        for (int e=0;e<EE;++e) p[e] /= sum;
        int i0=0; for (int e=1;e<EE;++e) if (p[e]>p[i0]) i0=e;
        int i1=-1;
        for (int e=0;e<EE;++e){ if (e==i0) continue; if (i1<0 || p[e]>p[i1]) i1=e; }
        float v0=p[i0], v1=p[i1], rsum=v0+v1;
        float w0=v0/rsum, w1=v1/rsum;
        for (int e=0;e<EE;++e){ probs[b*EE+e]=p[e]; combine[b*EE+e]=0.f; }
        combine[b*EE+i0]=w0; combine[b*EE+i1]=w1;
        topi[b*KKE]=i0; topi[b*KKE+1]=i1;
        topw[b*KKE]=w0; topw[b*KKE+1]=w1;
    }
}

// ---------------- aux loss ----------------
__global__ __launch_bounds__(256) void aux_kernel(const float* __restrict__ combine,
                                                  const float* __restrict__ probs,
                                                  float* __restrict__ aux_out){
    int tid = threadIdx.x; int e = tid>>6, b = tid&63;
    float m = combine[b*EE+e] > 0.f ? 1.f : 0.f;
    float p = probs[b*EE+e];
    #pragma unroll
    for (int o=32;o>0;o>>=1){ m += __shfl_down(m,o); p += __shfl_down(p,o); }
    __shared__ float sh[EE];
    if ((tid&63)==0) sh[e] = (m/(float)BB)*(p/(float)BB);
    __syncthreads();
    if (tid==0) aux_out[0] = (float)EE * (sh[0]+sh[1]+sh[2]+sh[3]);
}

// ---------------- token mixing v2: block = (b, 64-channel tile) ----------------
// W1/W2 traffic per block amortized over 64 channels; x/H tiles in LDS (bf16).
__global__ __launch_bounds__(256) void tokenmix2_kernel(
    const __hip_bfloat16* __restrict__ nbf, const float* __restrict__ x,
    const float* __restrict__ W1, const float* __restrict__ b1,
    const float* __restrict__ W2, const float* __restrict__ b2,
    const int* __restrict__ topi, const float* __restrict__ topw,
    float* __restrict__ x1)
{
    __shared__ __hip_bfloat16 xs[SS][64];
    __shared__ __hip_bfloat16 Hs[THH][64];
    int b = blockIdx.y, d0 = blockIdx.x*64;
    int tid = threadIdx.x, lane = tid&63, w = tid>>6;
    for (int s = w; s < SS; s += 4)
        xs[s][lane] = nbf[((size_t)b*SS + s)*DD + d0 + lane];
    #pragma unroll
    for (int k=0;k<KKE;++k){
        int e = __builtin_amdgcn_readfirstlane(topi[b*KKE+k]);
        float wgt = topw[b*KKE+k];
        __syncthreads();   // xs ready / previous phase2 done with Hs
        const float* W1e = W1 + (size_t)e*SS*THH;
        // phase1: Hs[h][lane] = gelu(sum_s xs[s][lane]*W1[e][s][h] + b1[e][h]), h = w+4j
        for (int hj=0; hj<13; ++hj){
            int hb = w + 16*hj;
            if (hj < 12){
                float a0=b1[e*THH+hb], a1=b1[e*THH+hb+4], a2=b1[e*THH+hb+8], a3=b1[e*THH+hb+12];
                for (int s=0;s<SS;++s){
                    float xv = __bfloat162float(xs[s][lane]);
                    const float* wr = W1e + (size_t)s*THH + hb;
                    a0 += xv*wr[0]; a1 += xv*wr[4]; a2 += xv*wr[8]; a3 += xv*wr[12];
                }
                Hs[hb][lane]    = __float2bfloat16(gelu_exact(a0));
                Hs[hb+4][lane]  = __float2bfloat16(gelu_exact(a1));
                Hs[hb+8][lane]  = __float2bfloat16(gelu_exact(a2));
                Hs[hb+12][lane] = __float2bfloat16(gelu_exact(a3));
            } else {
                float a0=b1[e*THH+hb];
                for (int s=0;s<SS;++s)
                    a0 += __bfloat162float(xs[s][lane]) * W1e[(size_t)s*THH + hb];
                Hs[hb][lane] = __float2bfloat16(gelu_exact(a0));
            }
        }
        __syncthreads();
        const float* W2e = W2 + (size_t)e*THH*SS;
        // phase2: o[s][lane] = sum_h Hs[h][lane]*W2[e][h][s] + b2[e][s], s = w+4j
        for (int sj=0; sj<13; ++sj){
            int sb = w + 16*sj;
            if (sj < 12){
                float o0=b2[e*SS+sb], o1=b2[e*SS+sb+4], o2=b2[e*SS+sb+8], o3=b2[e*SS+sb+12];
                for (int h=0;h<THH;++h){
                    float hv = __bfloat162float(Hs[h][lane]);
                    const float* wr = W2e + (size_t)h*SS + sb;
                    o0 += hv*wr[0]; o1 += hv*wr[4]; o2 += hv*wr[8]; o3 += hv*wr[12];
                }
                float ov[4] = {o0,o1,o2,o3};
                #pragma unroll
                for (int u=0;u<4;++u){
                    size_t idx = ((size_t)b*SS + sb + 4*u)*DD + d0 + lane;
                    float val = wgt*ov[u];
                    if (k==0) x1[idx] = x[idx] + val; else x1[idx] += val;
                }
            } else {
                float o0=b2[e*SS+sb];
                for (int h=0;h<THH;++h)
                    o0 += __bfloat162float(Hs[h][lane]) * W2e[(size_t)h*SS + sb];
                size_t idx = ((size_t)b*SS + sb)*DD + d0 + lane;
                float val = wgt*o0;
                if (k==0) x1[idx] = x[idx] + val; else x1[idx] += val;
            }
        }
    }
}

// ---------------- tiled MFMA GEMM, B^T input: C[M][Ntot] = A[M][K] @ Bt[N][K]^T ----------------
// 128x128 tile, BK=64, 256 thr (4 waves 2x2), XOR-swizzled LDS, register prefetch.
// EPI 0: Hout = bf16(gelu(acc+bias));  EPI 1: Cio += acc + bias.
template<int KDIM, int EPI>
__global__ __launch_bounds__(256) void gemm_bt_kernel(
    const __hip_bfloat16* __restrict__ A,
    const __hip_bfloat16* __restrict__ Bt,
    const float* __restrict__ bias,
    __hip_bfloat16* __restrict__ Hout,
    float* __restrict__ Cio,
    int Ntot)
{
    __shared__ __hip_bfloat16 As[128*64];
    __shared__ __hip_bfloat16 Bs[128*64];
    int tid = threadIdx.x, lane = tid&63, w = tid>>6;
    int wm = w>>1, wn = w&1;
    int l15 = lane&15, l4 = lane>>4;
    int m0 = blockIdx.y*128, n0 = blockIdx.x*128;
    f32x4 acc[4][4];
    #pragma unroll
    for (int mi=0;mi<4;++mi)
        #pragma unroll
        for (int ni=0;ni<4;++ni) acc[mi][ni] = (f32x4){0.f,0.f,0.f,0.f};

    int srow = w*32 + (lane>>3);       // staged row (this thread, i-step adds 8)
    int sc   = lane&7;                 // source k-chunk (16B units)
    int soff = srow*64 + ((sc ^ (srow&7))<<3);   // swizzled LDS element offset
    const __hip_bfloat16* Ap = A  + (size_t)(m0+srow)*KDIM + sc*8;
    const __hip_bfloat16* Bp = Bt + (size_t)(n0+srow)*KDIM + sc*8;

    bf16x8 va[4], vb[4];
    #pragma unroll
    for (int i=0;i<4;++i){
        va[i] = *reinterpret_cast<const bf16x8*>(Ap + (size_t)i*8*KDIM);
        vb[i] = *reinterpret_cast<const bf16x8*>(Bp + (size_t)i*8*KDIM);
    }
    for (int k0=0; k0<KDIM; k0+=64){
        __syncthreads();   // previous compute finished with LDS
        #pragma unroll
        for (int i=0;i<4;++i){
            *reinterpret_cast<bf16x8*>(&As[soff + i*8*64]) = va[i];
            *reinterpret_cast<bf16x8*>(&Bs[soff + i*8*64]) = vb[i];
        }
        __syncthreads();
        if (k0+64 < KDIM){
            #pragma unroll
            for (int i=0;i<4;++i){
                va[i] = *reinterpret_cast<const bf16x8*>(Ap + (size_t)i*8*KDIM + (k0+64));
                vb[i] = *reinterpret_cast<const bf16x8*>(Bp + (size_t)i*8*KDIM + (k0+64));
            }
        }
        #pragma unroll
        for (int kk=0;kk<2;++kk){
            bf16x8 af[4], bfr[4];
            #pragma unroll
            for (int mi=0;mi<4;++mi){
                int r = wm*64 + mi*16 + l15;
                int kc = kk*4 + l4;
                af[mi] = *reinterpret_cast<const bf16x8*>(&As[r*64 + ((kc ^ (r&7))<<3)]);
            }
            #pragma unroll
            for (int ni=0;ni<4;++ni){
                int r = wn*64 + ni*16 + l15;
                int kc = kk*4 + l4;
                bfr[ni] = *reinterpret_cast<const bf16x8*>(&Bs[r*64 + ((kc ^ (r&7))<<3)]);
            }
            #pragma unroll
            for (int mi=0;mi<4;++mi)
                #pragma unroll
                for (int ni=0;ni<4;++ni)
                    acc[mi][ni] = __builtin_amdgcn_mfma_f32_16x16x32_bf16(af[mi], bfr[ni], acc[mi][ni], 0, 0, 0);
        }
    }
    #pragma unroll
    for (int mi=0;mi<4;++mi){
        #pragma unroll
        for (int ni=0;ni<4;++ni){
            int col = n0 + wn*64 + ni*16 + l15;
            float bv = bias[col];
            #pragma unroll
            for (int r=0;r<4;++r){
                int row = m0 + wm*64 + mi*16 + l4*4 + r;
                if (EPI==0)
                    Hout[(size_t)row*Ntot + col] = __float2bfloat16(gelu_exact(acc[mi][ni][r] + bv));
                else
                    Cio[(size_t)row*Ntot + col] += acc[mi][ni][r] + bv;
            }
        }
    }
}

// ---------------- fallback fused MLP (validated round 6) ----------------
__global__ __launch_bounds__(512, 4) void mlp_mfma_kernel(
    const __hip_bfloat16* __restrict__ n2b,
    const __hip_bfloat16* __restrict__ w1t,
    const float* __restrict__ bm1,
    const __hip_bfloat16* __restrict__ w2t,
    const float* __restrict__ bm2,
    float* __restrict__ io)
{
    __shared__ __align__(16) __hip_bfloat16 Ht[32*64];
    int tid = threadIdx.x;
    int wid = tid >> 6, lane = tid & 63;
    int wm = wid >> 2, wn = wid & 3;
    int l15 = lane & 15, l4 = lane >> 4;
    int m0 = blockIdx.x * 32;
    f32x4 acc[12];
    #pragma unroll
    for (int f=0; f<12; ++f) acc[f] = (f32x4){0.f,0.f,0.f,0.f};
    const __hip_bfloat16* aptr = n2b + (size_t)(m0 + wm*16 + l15)*DD + l4*8;
    for (int hc = 0; hc < MHH; hc += 64) {
        f32x4 h = (f32x4){0.f,0.f,0.f,0.f};
        const __hip_bfloat16* bptr = w1t + (size_t)(hc + wn*16 + l15)*DD + l4*8;
        #pragma unroll 4
        for (int ks = 0; ks < DD; ks += 32) {
            bf16x8 a = *reinterpret_cast<const bf16x8*>(aptr + ks);
            bf16x8 bb = *reinterpret_cast<const bf16x8*>(bptr + ks);
            h = __builtin_amdgcn_mfma_f32_16x16x32_bf16(a, bb, h, 0, 0, 0);
        }
        float bv = bm1[hc + wn*16 + l15];
        __syncthreads();
        {
            int col = wn*16 + l15;
            int chunk = col >> 3, inner = col & 7;
            #pragma unroll
            for (int r=0; r<4; ++r) {
                int row = wm*16 + l4*4 + r;
                float v = gelu_exact(h[r] + bv);
                Ht[row*64 + ((chunk ^ (row&7))<<3) + inner] = __float2bfloat16(v);
            }
        }
        __syncthreads();
        #pragma unroll
        for (int kk = 0; kk < 2; ++kk) {
            int arow = wm*16 + l15;
            int ach = (kk*32 + l4*8) >> 3;
            bf16x8 aH = *reinterpret_cast<const bf16x8*>(&Ht[arow*64 + ((ach ^ (arow&7))<<3)]);
            const __hip_bfloat16* b2p = w2t + (size_t)(wn*192 + l15)*MHH + hc + kk*32 + l4*8;
            #pragma unroll
            for (int f=0; f<12; ++f) {
                bf16x8 bb = *reinterpret_cast<const bf16x8*>(b2p + (size_t)f*16*MHH);
                acc[f] = __builtin_amdgcn_mfma_f32_16x16x32_bf16(aH, bb, acc[f], 0, 0, 0);
            }
        }
    }
    #pragma unroll
    for (int f=0; f<12; ++f) {
        int col = wn*192 + f*16 + l15;
        float b2v = bm2[col];
        #pragma unroll
        for (int r=0; r<4; ++r) {
            size_t idx = (size_t)(m0 + wm*16 + l4*4 + r)*DD + col;
            io[idx] += acc[f][r] + b2v;
        }
    }
}

extern "C" void kernel_launch(void* const* d_in, const int* in_sizes, int n_in,
                              void* d_out, int out_size, void* d_ws, size_t ws_size,
                              hipStream_t stream) {
    const float* x    = (const float*)d_in[0];
    const float* g1   = (const float*)d_in[1];
    const float* be1  = (const float*)d_in[2];
    const float* Wg   = (const float*)d_in[3];
    const float* bg   = (const float*)d_in[4];
    const float* W1   = (const float*)d_in[5];
    const float* b1e  = (const float*)d_in[6];
    const float* W2   = (const float*)d_in[7];
    const float* b2e  = (const float*)d_in[8];
    const float* g2   = (const float*)d_in[9];
    const float* be2  = (const float*)d_in[10];
    const float* Wm1  = (const float*)d_in[11];
    const float* bm1  = (const float*)d_in[12];
    const float* Wm2  = (const float*)d_in[13];
    const float* bm2  = (const float*)d_in[14];

    float* out = (float*)d_out;
    char* w = (char*)d_ws;

    const size_t OFF_W1T = 19267584;            // nbf: 12544*768*2
    const size_t OFF_W2T = OFF_W1T + 4718592;   // w1t: 3072*768*2
    const size_t OFF_H   = OFF_W2T + 4718592;   // w2t: 768*3072*2
    const size_t H_BYTES = (size_t)MM * MHH * 2;  // 77,070,336
    const size_t NEED_BIG = OFF_H + H_BYTES + 400000;
    bool bigws = (ws_size >= NEED_BIG);

    __hip_bfloat16* nbf = (__hip_bfloat16*)w;
    __hip_bfloat16* w1t = (__hip_bfloat16*)(w + OFF_W1T);
    __hip_bfloat16* w2t = (__hip_bfloat16*)(w + OFF_W2T);
    __hip_bfloat16* Hbuf = (__hip_bfloat16*)(w + OFF_H);
    size_t tail = bigws ? (OFF_H + H_BYTES) : OFF_H;
    float* muv     = (float*)(w + tail);          // 12544
    float* rsigv   = muv + MM;                    // 12544
    float* mv      = rsigv + MM;                  // 64*768
    float* combine = mv + (size_t)BB*DD;          // 256
    float* probs   = combine + BB*EE;             // 256
    float* topw    = probs + BB*EE;               // 128
    int*   topi    = (int*)(topw + BB*KKE);       // 128

    // 0) one-off weight transposes to bf16 [n][k]
    transpose_bf16_kernel<<<dim3(MHH/32, DD/32), 256, 0, stream>>>(Wm1, w1t, DD, MHH);
    transpose_bf16_kernel<<<dim3(DD/32, MHH/32), 256, 0, stream>>>(Wm2, w2t, MHH, DD);
    // 1) LN1 -> nbf (bf16) + stats
    ln_bf16_kernel<<<MM, 256, 0, stream>>>(x, g1, be1, nbf, muv, rsigv);
    // 2) router: parallel meanvec (exact fp32) + tiny logits/top-2
    meanvec_kernel<<<dim3(2, BB), 384, 0, stream>>>(x, muv, rsigv, g1, be1, mv);
    logits_kernel<<<BB, 64, 0, stream>>>(mv, Wg, bg, combine, probs, topi, topw);
    // 3) aux loss -> out[N1]
    aux_kernel<<<1, 256, 0, stream>>>(combine, probs, out + N1);
    // 4) token mixing + residual -> x1 in d_out
    tokenmix2_kernel<<<dim3(DD/64, BB), 256, 0, stream>>>(nbf, x, W1, b1e, W2, b2e,
                                                          topi, topw, out);
    // 5) LN2(x1) -> nbf
    ln_bf16_kernel<<<MM, 256, 0, stream>>>(out, g2, be2, nbf, muv, rsigv);
    // 6) channel MLP
    if (bigws){
        gemm_bt_kernel<DD, 0><<<dim3(MHH/128, MM/128), 256, 0, stream>>>(
            nbf, w1t, bm1, Hbuf, nullptr, MHH);
        gemm_bt_kernel<MHH, 1><<<dim3(DD/128, MM/128), 256, 0, stream>>>(
            Hbuf, w2t, bm2, nullptr, out, DD);
    } else {
        mlp_mfma_kernel<<<MM/32, 512, 0, stream>>>(nbf, w1t, bm1, w2t, bm2, out);
    }
}

// Round 9
// 383.545 us; speedup vs baseline: 24.4078x; 2.9933x over previous
//
#include <hip/hip_runtime.h>
#include <hip/hip_bf16.h>
#include <math.h>

#define BB 64
#define SS 196
#define DD 768
#define EE 4
#define KKE 2
#define THH 196
#define MHH 3072
#define N1 (BB*SS*DD)
#define MM (BB*SS)
#define PP 256   // padded S/TH for token-mix GEMMs

typedef __bf16 bf16x8 __attribute__((ext_vector_type(8)));
typedef float f32x4 __attribute__((ext_vector_type(4)));

__device__ __forceinline__ float gelu_exact(float x){
    return 0.5f * x * (1.0f + erff(x * 0.70710678118654752f));
}

// ---------------- LN over last dim -> bf16 out, save mu/rsig ----------------
__global__ __launch_bounds__(256) void ln_bf16_kernel(const float* __restrict__ x,
                                                      const float* __restrict__ g,
                                                      const float* __restrict__ b,
                                                      __hip_bfloat16* __restrict__ out,
                                                      float* __restrict__ muo,
                                                      float* __restrict__ rso){
    int row = blockIdx.x;
    int tid = threadIdx.x;
    const float* xr = x + (size_t)row * DD;
    float v0 = xr[tid], v1 = xr[tid+256], v2 = xr[tid+512];
    float s = v0+v1+v2, ss = v0*v0+v1*v1+v2*v2;
    __shared__ float sh[10];
    int lane = tid & 63, wid = tid >> 6;
    #pragma unroll
    for (int o=32;o>0;o>>=1){ s += __shfl_down(s,o); ss += __shfl_down(ss,o); }
    if (lane==0){ sh[wid]=s; sh[4+wid]=ss; }
    __syncthreads();
    if (tid==0){
        float S1=sh[0]+sh[1]+sh[2]+sh[3], S2=sh[4]+sh[5]+sh[6]+sh[7];
        float mu = S1/DD; float var = S2/DD - mu*mu;
        float rs = rsqrtf(var + 1e-6f);
        sh[8]=mu; sh[9]=rs;
        muo[row]=mu; rso[row]=rs;
    }
    __syncthreads();
    float mu=sh[8], rs=sh[9];
    __hip_bfloat16* orow = out + (size_t)row*DD;
    orow[tid]     = __float2bfloat16((v0-mu)*rs*g[tid]     + b[tid]);
    orow[tid+256] = __float2bfloat16((v1-mu)*rs*g[tid+256] + b[tid+256]);
    orow[tid+512] = __float2bfloat16((v2-mu)*rs*g[tid+512] + b[tid+512]);
}

// ---------------- fp32 transpose -> bf16: dst[c][r] = src[r][c] (exact dims) ----------------
__global__ __launch_bounds__(256) void transpose_bf16_kernel(const float* __restrict__ src,
                                                             __hip_bfloat16* __restrict__ dst,
                                                             int R, int C){
    __shared__ float t[32][33];
    int c0 = blockIdx.x*32, r0 = blockIdx.y*32;
    int tx = threadIdx.x & 31, ty = threadIdx.x >> 5;
    #pragma unroll
    for (int rr = ty; rr < 32; rr += 8)
        t[rr][tx] = src[(size_t)(r0+rr)*C + c0 + tx];
    __syncthreads();
    #pragma unroll
    for (int cc = ty; cc < 32; cc += 8)
        dst[(size_t)(c0+cc)*R + r0 + tx] = __float2bfloat16(t[tx][cc]);
}

// ---------------- fp32 [R][C] -> bf16 transposed+padded [P][P]; z = expert ----------------
__global__ __launch_bounds__(256) void transpose_pad_w_kernel(const float* __restrict__ src0,
                                                              __hip_bfloat16* __restrict__ dst0,
                                                              int R, int C){
    const float* src = src0 + (size_t)blockIdx.z*R*C;
    __hip_bfloat16* dst = dst0 + (size_t)blockIdx.z*PP*PP;
    __shared__ float t[32][33];
    int c0 = blockIdx.x*32, r0 = blockIdx.y*32;
    int tx = threadIdx.x & 31, ty = threadIdx.x >> 5;
    #pragma unroll
    for (int rr = ty; rr < 32; rr += 8)
        t[rr][tx] = (r0+rr < R && c0+tx < C) ? src[(size_t)(r0+rr)*C + c0 + tx] : 0.f;
    __syncthreads();
    #pragma unroll
    for (int cc = ty; cc < 32; cc += 8)
        dst[(size_t)(c0+cc)*PP + r0 + tx] = __float2bfloat16(t[tx][cc]);
}

// ---------------- nbf [64][196][768] -> nTp [64][768][256] (transpose + zero-pad s) ----------------
__global__ __launch_bounds__(256) void transpose_pad_n_kernel(const __hip_bfloat16* __restrict__ src,
                                                              __hip_bfloat16* __restrict__ dst){
    int b = blockIdx.z;
    __shared__ __hip_bfloat16 t[64][66];
    int d0 = blockIdx.x*64, s0 = blockIdx.y*64;
    int lane = threadIdx.x & 63, q = threadIdx.x >> 6;
    for (int i=q; i<64; i+=4){
        int s = s0+i;
        t[i][lane] = (s < SS) ? src[((size_t)b*SS + s)*DD + d0 + lane]
                              : __float2bfloat16(0.f);
    }
    __syncthreads();
    for (int i=q; i<64; i+=4){
        int d = d0+i;
        dst[((size_t)b*DD + d)*PP + s0 + lane] = t[lane][i];
    }
}

// ---------------- meanvec: mv[b][d] = g1[d]*mean_s((x-mu)*rs) + b1[d], exact fp32 ----------------
__global__ __launch_bounds__(384) void meanvec_kernel(const float* __restrict__ x,
                                                      const float* __restrict__ mu,
                                                      const float* __restrict__ rs,
                                                      const float* __restrict__ g1,
                                                      const float* __restrict__ b1,
                                                      float* __restrict__ mv){
    int b = blockIdx.y, d = blockIdx.x*384 + threadIdx.x;
    __shared__ float smu[SS], srs[SS];
    for (int s=threadIdx.x; s<SS; s+=384){ smu[s]=mu[b*SS+s]; srs[s]=rs[b*SS+s]; }
    __syncthreads();
    const float* base = x + (size_t)b*SS*DD + d;
    float a0=0.f, a1=0.f;
    for (int s=0;s<SS;s+=2){
        a0 += (base[(size_t)s*DD]     - smu[s])  * srs[s];
        a1 += (base[(size_t)(s+1)*DD] - smu[s+1])* srs[s+1];
    }
    mv[(size_t)b*DD + d] = g1[d]*((a0+a1)/(float)SS) + b1[d];
}

// ---------------- logits + softmax + top-2 (one wave per batch) ----------------
__global__ __launch_bounds__(64) void logits_kernel(const float* __restrict__ mv,
                                                    const float* __restrict__ Wg,
                                                    const float* __restrict__ bg,
                                                    float* __restrict__ combine,
                                                    float* __restrict__ probs,
                                                    int* __restrict__ topi,
                                                    float* __restrict__ topw){
    int b = blockIdx.x, lane = threadIdx.x;
    float pl[EE] = {0.f,0.f,0.f,0.f};
    #pragma unroll
    for (int i=0;i<DD/64;++i){
        int d = lane + i*64;
        float m = mv[(size_t)b*DD + d];
        #pragma unroll
        for (int e=0;e<EE;++e) pl[e] += m * Wg[d*EE + e];
    }
    #pragma unroll
    for (int e=0;e<EE;++e){
        #pragma unroll
        for (int o=32;o>0;o>>=1) pl[e] += __shfl_down(pl[e], o);
    }
    if (lane==0){
        float lg[EE];
        for (int e=0;e<EE;++e) lg[e] = pl[e] + bg[e];
        float mx = lg[0];
        for (int e=1;e<EE;++e) mx = fmaxf(mx, lg[e]);
        float p[EE]; float sum=0.f;
        for (int e=0;e<EE;++e){ p[e]=expf(lg[e]-mx); sum+=p[e]; }
        for (int e=0;e<EE;++e) p[e] /= sum;
        int i0=0; for (int e=1;e<EE;++e) if (p[e]>p[i0]) i0=e;
        int i1=-1;
        for (int e=0;e<EE;++e){ if (e==i0) continue; if (i1<0 || p[e]>p[i1]) i1=e; }
        float v0=p[i0], v1=p[i1], rsum=v0+v1;
        float w0=v0/rsum, w1=v1/rsum;
        for (int e=0;e<EE;++e){ probs[b*EE+e]=p[e]; combine[b*EE+e]=0.f; }
        combine[b*EE+i0]=w0; combine[b*EE+i1]=w1;
        topi[b*KKE]=i0; topi[b*KKE+1]=i1;
        topw[b*KKE]=w0; topw[b*KKE+1]=w1;
    }
}

// ---------------- aux loss ----------------
__global__ __launch_bounds__(256) void aux_kernel(const float* __restrict__ combine,
                                                  const float* __restrict__ probs,
                                                  float* __restrict__ aux_out){
    int tid = threadIdx.x; int e = tid>>6, b = tid&63;
    float m = combine[b*EE+e] > 0.f ? 1.f : 0.f;
    float p = probs[b*EE+e];
    #pragma unroll
    for (int o=32;o>0;o>>=1){ m += __shfl_down(m,o); p += __shfl_down(p,o); }
    __shared__ float sh[EE];
    if ((tid&63)==0) sh[e] = (m/(float)BB)*(p/(float)BB);
    __syncthreads();
    if (tid==0) aux_out[0] = (float)EE * (sh[0]+sh[1]+sh[2]+sh[3]);
}

// ---------------- tok GEMM1: htok[be][768][256] = gelu(nTp[b] @ w1tp[e]^T + b1[e]), pad cols = 0 ----
__global__ __launch_bounds__(256) void tok_gemm1_kernel(
    const __hip_bfloat16* __restrict__ nTp,   // [64][768][256]
    const __hip_bfloat16* __restrict__ w1tp,  // [4][256][256] = W1^T padded
    const float* __restrict__ b1,             // [4][196]
    const int* __restrict__ topi,
    __hip_bfloat16* __restrict__ htok)        // [128][768][256]
{
    __shared__ __hip_bfloat16 As[128*64];
    __shared__ __hip_bfloat16 Bs[128*64];
    int tid=threadIdx.x, lane=tid&63, w=tid>>6;
    int wm=w>>1, wn=w&1, l15=lane&15, l4=lane>>4;
    int be = blockIdx.z, b = be>>1;
    int e = __builtin_amdgcn_readfirstlane(topi[b*KKE + (be&1)]);
    int m0 = blockIdx.y*128, n0 = blockIdx.x*128;
    const __hip_bfloat16* A  = nTp  + ((size_t)b*DD + m0)*PP;
    const __hip_bfloat16* Bt = w1tp + ((size_t)e*PP + n0)*PP;
    f32x4 acc[4][4];
    #pragma unroll
    for (int mi=0;mi<4;++mi)
        #pragma unroll
        for (int ni=0;ni<4;++ni) acc[mi][ni] = (f32x4){0.f,0.f,0.f,0.f};

    int srow = w*32 + (lane>>3), sc = lane&7;
    int soff = srow*64 + ((sc ^ (srow&7))<<3);
    const __hip_bfloat16* Ap = A + (size_t)srow*PP + sc*8;
    const __hip_bfloat16* Bp = Bt + (size_t)srow*PP + sc*8;
    bf16x8 va[4], vb[4];
    #pragma unroll
    for (int i=0;i<4;++i){
        va[i] = *reinterpret_cast<const bf16x8*>(Ap + (size_t)i*8*PP);
        vb[i] = *reinterpret_cast<const bf16x8*>(Bp + (size_t)i*8*PP);
    }
    for (int k0=0; k0<PP; k0+=64){
        __syncthreads();
        #pragma unroll
        for (int i=0;i<4;++i){
            *reinterpret_cast<bf16x8*>(&As[soff + i*8*64]) = va[i];
            *reinterpret_cast<bf16x8*>(&Bs[soff + i*8*64]) = vb[i];
        }
        __syncthreads();
        if (k0+64 < PP){
            #pragma unroll
            for (int i=0;i<4;++i){
                va[i] = *reinterpret_cast<const bf16x8*>(Ap + (size_t)i*8*PP + (k0+64));
                vb[i] = *reinterpret_cast<const bf16x8*>(Bp + (size_t)i*8*PP + (k0+64));
            }
        }
        #pragma unroll
        for (int kk=0;kk<2;++kk){
            bf16x8 af[4], bfr[4];
            #pragma unroll
            for (int mi=0;mi<4;++mi){
                int r = wm*64 + mi*16 + l15, kc = kk*4 + l4;
                af[mi] = *reinterpret_cast<const bf16x8*>(&As[r*64 + ((kc ^ (r&7))<<3)]);
            }
            #pragma unroll
            for (int ni=0;ni<4;++ni){
                int r = wn*64 + ni*16 + l15, kc = kk*4 + l4;
                bfr[ni] = *reinterpret_cast<const bf16x8*>(&Bs[r*64 + ((kc ^ (r&7))<<3)]);
            }
            #pragma unroll
            for (int mi=0;mi<4;++mi)
                #pragma unroll
                for (int ni=0;ni<4;++ni)
                    acc[mi][ni] = __builtin_amdgcn_mfma_f32_16x16x32_bf16(af[mi], bfr[ni], acc[mi][ni], 0, 0, 0);
        }
    }
    #pragma unroll
    for (int mi=0;mi<4;++mi){
        #pragma unroll
        for (int ni=0;ni<4;++ni){
            int col = n0 + wn*64 + ni*16 + l15;
            float bv = (col < THH) ? b1[e*THH + col] : 0.f;
            #pragma unroll
            for (int r=0;r<4;++r){
                int row = m0 + wm*64 + mi*16 + l4*4 + r;
                float v = (col < THH) ? gelu_exact(acc[mi][ni][r] + bv) : 0.f;
                htok[((size_t)be*DD + row)*PP + col] = __float2bfloat16(v);
            }
        }
    }
}

// ---------------- tok GEMM2: x1[b][s][d] = x + sum_k wk*(htok[b,k] @ w2tp[ek]^T + b2[ek]) ----------
__global__ __launch_bounds__(256) void tok_gemm2_kernel(
    const __hip_bfloat16* __restrict__ htok,  // [128][768][256]
    const __hip_bfloat16* __restrict__ w2tp,  // [4][256][256] = W2^T padded
    const float* __restrict__ b2,             // [4][196]
    const int* __restrict__ topi, const float* __restrict__ topw,
    const float* __restrict__ x, float* __restrict__ x1)
{
    __shared__ __hip_bfloat16 As[128*64];
    __shared__ __hip_bfloat16 Bs[128*64];
    int tid=threadIdx.x, lane=tid&63, w=tid>>6;
    int wm=w>>1, wn=w&1, l15=lane&15, l4=lane>>4;
    int b = blockIdx.z;
    int m0 = blockIdx.y*128, n0 = blockIdx.x*128;
    float w0 = topw[b*KKE], w1 = topw[b*KKE+1];
    f32x4 acc[4][4];
    #pragma unroll
    for (int mi=0;mi<4;++mi)
        #pragma unroll
        for (int ni=0;ni<4;++ni) acc[mi][ni] = (f32x4){0.f,0.f,0.f,0.f};

    int srow = w*32 + (lane>>3), sc = lane&7;
    int soff = srow*64 + ((sc ^ (srow&7))<<3);

    for (int pass=0; pass<2; ++pass){
        int e = __builtin_amdgcn_readfirstlane(topi[b*KKE + pass]);
        const __hip_bfloat16* Ap = htok + ((size_t)(b*KKE+pass)*DD + m0 + srow)*PP + sc*8;
        const __hip_bfloat16* Bp = w2tp + ((size_t)e*PP + n0 + srow)*PP + sc*8;
        bf16x8 va[4], vb[4];
        #pragma unroll
        for (int i=0;i<4;++i){
            va[i] = *reinterpret_cast<const bf16x8*>(Ap + (size_t)i*8*PP);
            vb[i] = *reinterpret_cast<const bf16x8*>(Bp + (size_t)i*8*PP);
        }
        for (int k0=0; k0<PP; k0+=64){
            __syncthreads();
            #pragma unroll
            for (int i=0;i<4;++i){
                *reinterpret_cast<bf16x8*>(&As[soff + i*8*64]) = va[i];
                *reinterpret_cast<bf16x8*>(&Bs[soff + i*8*64]) = vb[i];
            }
            __syncthreads();
            if (k0+64 < PP){
                #pragma unroll
                for (int i=0;i<4;++i){
                    va[i] = *reinterpret_cast<const bf16x8*>(Ap + (size_t)i*8*PP + (k0+64));
                    vb[i] = *reinterpret_cast<const bf16x8*>(Bp + (size_t)i*8*PP + (k0+64));
                }
            }
            #pragma unroll
            for (int kk=0;kk<2;++kk){
                bf16x8 af[4], bfr[4];
                #pragma unroll
                for (int mi=0;mi<4;++mi){
                    int r = wm*64 + mi*16 + l15, kc = kk*4 + l4;
                    af[mi] = *reinterpret_cast<const bf16x8*>(&As[r*64 + ((kc ^ (r&7))<<3)]);
                }
                #pragma unroll
                for (int ni=0;ni<4;++ni){
                    int r = wn*64 + ni*16 + l15, kc = kk*4 + l4;
                    bfr[ni] = *reinterpret_cast<const bf16x8*>(&Bs[r*64 + ((kc ^ (r&7))<<3)]);
                }
                #pragma unroll
                for (int mi=0;mi<4;++mi)
                    #pragma unroll
                    for (int ni=0;ni<4;++ni)
                        acc[mi][ni] = __builtin_amdgcn_mfma_f32_16x16x32_bf16(af[mi], bfr[ni], acc[mi][ni], 0, 0, 0);
            }
        }
        if (pass==0){
            float sc0 = w0 / w1;   // softmax top-2 renorm => w1 > 0
            #pragma unroll
            for (int mi=0;mi<4;++mi)
                #pragma unroll
                for (int ni=0;ni<4;++ni)
                    #pragma unroll
                    for (int r=0;r<4;++r) acc[mi][ni][r] *= sc0;
        }
    }
    int e0 = topi[b*KKE], e1 = topi[b*KKE+1];
    #pragma unroll
    for (int mi=0;mi<4;++mi){
        #pragma unroll
        for (int ni=0;ni<4;++ni){
            int col = n0 + wn*64 + ni*16 + l15;   // s index
            if (col < SS){
                float bias = w0*b2[e0*SS+col] + w1*b2[e1*SS+col];
                int rowb = m0 + wm*64 + mi*16 + l4*4;
                size_t idx = ((size_t)b*SS + col)*DD + rowb;
                f32x4 xv = *reinterpret_cast<const f32x4*>(x + idx);
                f32x4 res;
                #pragma unroll
                for (int r=0;r<4;++r) res[r] = xv[r] + w1*acc[mi][ni][r] + bias;
                *reinterpret_cast<f32x4*>(x1 + idx) = res;
            }
        }
    }
}

// ---------------- token mixing fallback (round-7 kernel) ----------------
__global__ __launch_bounds__(256) void tokenmix2_kernel(
    const __hip_bfloat16* __restrict__ nbf, const float* __restrict__ x,
    const float* __restrict__ W1, const float* __restrict__ b1,
    const float* __restrict__ W2, const float* __restrict__ b2,
    const int* __restrict__ topi, const float* __restrict__ topw,
    float* __restrict__ x1)
{
    __shared__ __hip_bfloat16 xs[SS][64];
    __shared__ __hip_bfloat16 Hs[THH][64];
    int b = blockIdx.y, d0 = blockIdx.x*64;
    int tid = threadIdx.x, lane = tid&63, w = tid>>6;
    for (int s = w; s < SS; s += 4)
        xs[s][lane] = nbf[((size_t)b*SS + s)*DD + d0 + lane];
    #pragma unroll
    for (int k=0;k<KKE;++k){
        int e = __builtin_amdgcn_readfirstlane(topi[b*KKE+k]);
        float wgt = topw[b*KKE+k];
        __syncthreads();
        const float* W1e = W1 + (size_t)e*SS*THH;
        for (int hj=0; hj<13; ++hj){
            int hb = w + 16*hj;
            if (hj < 12){
                float a0=b1[e*THH+hb], a1=b1[e*THH+hb+4], a2=b1[e*THH+hb+8], a3=b1[e*THH+hb+12];
                for (int s=0;s<SS;++s){
                    float xv = __bfloat162float(xs[s][lane]);
                    const float* wr = W1e + (size_t)s*THH + hb;
                    a0 += xv*wr[0]; a1 += xv*wr[4]; a2 += xv*wr[8]; a3 += xv*wr[12];
                }
                Hs[hb][lane]    = __float2bfloat16(gelu_exact(a0));
                Hs[hb+4][lane]  = __float2bfloat16(gelu_exact(a1));
                Hs[hb+8][lane]  = __float2bfloat16(gelu_exact(a2));
                Hs[hb+12][lane] = __float2bfloat16(gelu_exact(a3));
            } else {
                float a0=b1[e*THH+hb];
                for (int s=0;s<SS;++s)
                    a0 += __bfloat162float(xs[s][lane]) * W1e[(size_t)s*THH + hb];
                Hs[hb][lane] = __float2bfloat16(gelu_exact(a0));
            }
        }
        __syncthreads();
        const float* W2e = W2 + (size_t)e*THH*SS;
        for (int sj=0; sj<13; ++sj){
            int sb = w + 16*sj;
            if (sj < 12){
                float o0=b2[e*SS+sb], o1=b2[e*SS+sb+4], o2=b2[e*SS+sb+8], o3=b2[e*SS+sb+12];
                for (int h=0;h<THH;++h){
                    float hv = __bfloat162float(Hs[h][lane]);
                    const float* wr = W2e + (size_t)h*SS + sb;
                    o0 += hv*wr[0]; o1 += hv*wr[4]; o2 += hv*wr[8]; o3 += hv*wr[12];
                }
                float ov[4] = {o0,o1,o2,o3};
                #pragma unroll
                for (int u=0;u<4;++u){
                    size_t idx = ((size_t)b*SS + sb + 4*u)*DD + d0 + lane;
                    float val = wgt*ov[u];
                    if (k==0) x1[idx] = x[idx] + val; else x1[idx] += val;
                }
            } else {
                float o0=b2[e*SS+sb];
                for (int h=0;h<THH;++h)
                    o0 += __bfloat162float(Hs[h][lane]) * W2e[(size_t)h*SS + sb];
                size_t idx = ((size_t)b*SS + sb)*DD + d0 + lane;
                float val = wgt*o0;
                if (k==0) x1[idx] = x[idx] + val; else x1[idx] += val;
            }
        }
    }
}

// ---------------- tiled MFMA GEMM, B^T input (channel MLP) ----------------
template<int KDIM, int EPI>
__global__ __launch_bounds__(256) void gemm_bt_kernel(
    const __hip_bfloat16* __restrict__ A,
    const __hip_bfloat16* __restrict__ Bt,
    const float* __restrict__ bias,
    __hip_bfloat16* __restrict__ Hout,
    float* __restrict__ Cio,
    int Ntot)
{
    __shared__ __hip_bfloat16 As[128*64];
    __shared__ __hip_bfloat16 Bs[128*64];
    int tid = threadIdx.x, lane = tid&63, w = tid>>6;
    int wm = w>>1, wn = w&1;
    int l15 = lane&15, l4 = lane>>4;
    int m0 = blockIdx.y*128, n0 = blockIdx.x*128;
    f32x4 acc[4][4];
    #pragma unroll
    for (int mi=0;mi<4;++mi)
        #pragma unroll
        for (int ni=0;ni<4;++ni) acc[mi][ni] = (f32x4){0.f,0.f,0.f,0.f};

    int srow = w*32 + (lane>>3);
    int sc   = lane&7;
    int soff = srow*64 + ((sc ^ (srow&7))<<3);
    const __hip_bfloat16* Ap = A  + (size_t)(m0+srow)*KDIM + sc*8;
    const __hip_bfloat16* Bp = Bt + (size_t)(n0+srow)*KDIM + sc*8;

    bf16x8 va[4], vb[4];
    #pragma unroll
    for (int i=0;i<4;++i){
        va[i] = *reinterpret_cast<const bf16x8*>(Ap + (size_t)i*8*KDIM);
        vb[i] = *reinterpret_cast<const bf16x8*>(Bp + (size_t)i*8*KDIM);
    }
    for (int k0=0; k0<KDIM; k0+=64){
        __syncthreads();
        #pragma unroll
        for (int i=0;i<4;++i){
            *reinterpret_cast<bf16x8*>(&As[soff + i*8*64]) = va[i];
            *reinterpret_cast<bf16x8*>(&Bs[soff + i*8*64]) = vb[i];
        }
        __syncthreads();
        if (k0+64 < KDIM){
            #pragma unroll
            for (int i=0;i<4;++i){
                va[i] = *reinterpret_cast<const bf16x8*>(Ap + (size_t)i*8*KDIM + (k0+64));
                vb[i] = *reinterpret_cast<const bf16x8*>(Bp + (size_t)i*8*KDIM + (k0+64));
            }
        }
        #pragma unroll
        for (int kk=0;kk<2;++kk){
            bf16x8 af[4], bfr[4];
            #pragma unroll
            for (int mi=0;mi<4;++mi){
                int r = wm*64 + mi*16 + l15;
                int kc = kk*4 + l4;
                af[mi] = *reinterpret_cast<const bf16x8*>(&As[r*64 + ((kc ^ (r&7))<<3)]);
            }
            #pragma unroll
            for (int ni=0;ni<4;++ni){
                int r = wn*64 + ni*16 + l15;
                int kc = kk*4 + l4;
                bfr[ni] = *reinterpret_cast<const bf16x8*>(&Bs[r*64 + ((kc ^ (r&7))<<3)]);
            }
            #pragma unroll
            for (int mi=0;mi<4;++mi)
                #pragma unroll
                for (int ni=0;ni<4;++ni)
                    acc[mi][ni] = __builtin_amdgcn_mfma_f32_16x16x32_bf16(af[mi], bfr[ni], acc[mi][ni], 0, 0, 0);
        }
    }
    #pragma unroll
    for (int mi=0;mi<4;++mi){
        #pragma unroll
        for (int ni=0;ni<4;++ni){
            int col = n0 + wn*64 + ni*16 + l15;
            float bv = bias[col];
            #pragma unroll
            for (int r=0;r<4;++r){
                int row = m0 + wm*64 + mi*16 + l4*4 + r;
                if (EPI==0)
                    Hout[(size_t)row*Ntot + col] = __float2bfloat16(gelu_exact(acc[mi][ni][r] + bv));
                else
                    Cio[(size_t)row*Ntot + col] += acc[mi][ni][r] + bv;
            }
        }
    }
}

// ---------------- fallback fused MLP (validated round 6) ----------------
__global__ __launch_bounds__(512, 4) void mlp_mfma_kernel(
    const __hip_bfloat16* __restrict__ n2b,
    const __hip_bfloat16* __restrict__ w1t,
    const float* __restrict__ bm1,
    const __hip_bfloat16* __restrict__ w2t,
    const float* __restrict__ bm2,
    float* __restrict__ io)
{
    __shared__ __align__(16) __hip_bfloat16 Ht[32*64];
    int tid = threadIdx.x;
    int wid = tid >> 6, lane = tid & 63;
    int wm = wid >> 2, wn = wid & 3;
    int l15 = lane & 15, l4 = lane >> 4;
    int m0 = blockIdx.x * 32;
    f32x4 acc[12];
    #pragma unroll
    for (int f=0; f<12; ++f) acc[f] = (f32x4){0.f,0.f,0.f,0.f};
    const __hip_bfloat16* aptr = n2b + (size_t)(m0 + wm*16 + l15)*DD + l4*8;
    for (int hc = 0; hc < MHH; hc += 64) {
        f32x4 h = (f32x4){0.f,0.f,0.f,0.f};
        const __hip_bfloat16* bptr = w1t + (size_t)(hc + wn*16 + l15)*DD + l4*8;
        #pragma unroll 4
        for (int ks = 0; ks < DD; ks += 32) {
            bf16x8 a = *reinterpret_cast<const bf16x8*>(aptr + ks);
            bf16x8 bb = *reinterpret_cast<const bf16x8*>(bptr + ks);
            h = __builtin_amdgcn_mfma_f32_16x16x32_bf16(a, bb, h, 0, 0, 0);
        }
        float bv = bm1[hc + wn*16 + l15];
        __syncthreads();
        {
            int col = wn*16 + l15;
            int chunk = col >> 3, inner = col & 7;
            #pragma unroll
            for (int r=0; r<4; ++r) {
                int row = wm*16 + l4*4 + r;
                float v = gelu_exact(h[r] + bv);
                Ht[row*64 + ((chunk ^ (row&7))<<3) + inner] = __float2bfloat16(v);
            }
        }
        __syncthreads();
        #pragma unroll
        for (int kk = 0; kk < 2; ++kk) {
            int arow = wm*16 + l15;
            int ach = (kk*32 + l4*8) >> 3;
            bf16x8 aH = *reinterpret_cast<const bf16x8*>(&Ht[arow*64 + ((ach ^ (arow&7))<<3)]);
            const __hip_bfloat16* b2p = w2t + (size_t)(wn*192 + l15)*MHH + hc + kk*32 + l4*8;
            #pragma unroll
            for (int f=0; f<12; ++f) {
                bf16x8 bb = *reinterpret_cast<const bf16x8*>(b2p + (size_t)f*16*MHH);
                acc[f] = __builtin_amdgcn_mfma_f32_16x16x32_bf16(aH, bb, acc[f], 0, 0, 0);
            }
        }
    }
    #pragma unroll
    for (int f=0; f<12; ++f) {
        int col = wn*192 + f*16 + l15;
        float b2v = bm2[col];
        #pragma unroll
        for (int r=0; r<4; ++r) {
            size_t idx = (size_t)(m0 + wm*16 + l4*4 + r)*DD + col;
            io[idx] += acc[f][r] + b2v;
        }
    }
}

extern "C" void kernel_launch(void* const* d_in, const int* in_sizes, int n_in,
                              void* d_out, int out_size, void* d_ws, size_t ws_size,
                              hipStream_t stream) {
    const float* x    = (const float*)d_in[0];
    const float* g1   = (const float*)d_in[1];
    const float* be1  = (const float*)d_in[2];
    const float* Wg   = (const float*)d_in[3];
    const float* bg   = (const float*)d_in[4];
    const float* W1   = (const float*)d_in[5];
    const float* b1e  = (const float*)d_in[6];
    const float* W2   = (const float*)d_in[7];
    const float* b2e  = (const float*)d_in[8];
    const float* g2   = (const float*)d_in[9];
    const float* be2  = (const float*)d_in[10];
    const float* Wm1  = (const float*)d_in[11];
    const float* bm1  = (const float*)d_in[12];
    const float* Wm2  = (const float*)d_in[13];
    const float* bm2  = (const float*)d_in[14];

    float* out = (float*)d_out;
    char* w = (char*)d_ws;

    // ---- ws layout (with aliasing): ----
    const size_t OFF_W1T  = 19267584;                 // nbf: 12544*768*2
    const size_t OFF_W2T  = OFF_W1T + 4718592;        // w1t (mlp)
    const size_t OFF_W1TP = OFF_W2T + 4718592;        // w2t (mlp)   -> 28,704,768
    const size_t OFF_W2TP = OFF_W1TP + (size_t)EE*PP*PP*2;   // +524,288
    const size_t OFF_REG  = OFF_W2TP + (size_t)EE*PP*PP*2;   // 29,753,344
    const size_t NTP_B    = (size_t)BB*DD*PP*2;       // 25,165,824
    const size_t HTOK_B   = (size_t)BB*KKE*DD*PP*2;   // 50,331,648
    const size_t HMLP_B   = (size_t)MM*MHH*2;         // 77,070,336
    const size_t REG_B    = (NTP_B + HTOK_B > HMLP_B) ? (NTP_B + HTOK_B) : HMLP_B;
    const size_t REG_END  = OFF_REG + REG_B;          // 106,823,680
    const size_t NEED     = REG_END + 400000;
    bool bigws = (ws_size >= NEED);

    __hip_bfloat16* nbf  = (__hip_bfloat16*)w;
    __hip_bfloat16* w1t  = (__hip_bfloat16*)(w + OFF_W1T);
    __hip_bfloat16* w2t  = (__hip_bfloat16*)(w + OFF_W2T);
    __hip_bfloat16* w1tp = (__hip_bfloat16*)(w + OFF_W1TP);
    __hip_bfloat16* w2tp = (__hip_bfloat16*)(w + OFF_W2TP);
    __hip_bfloat16* nTp  = (__hip_bfloat16*)(w + OFF_REG);
    __hip_bfloat16* htok = (__hip_bfloat16*)(w + OFF_REG + NTP_B);
    __hip_bfloat16* Hmlp = (__hip_bfloat16*)(w + OFF_REG);

    size_t tail = bigws ? REG_END : OFF_W1TP;
    float* muv     = (float*)(w + tail);
    float* rsigv   = muv + MM;
    float* mv      = rsigv + MM;
    float* combine = mv + (size_t)BB*DD;
    float* probs   = combine + BB*EE;
    float* topw    = probs + BB*EE;
    int*   topi    = (int*)(topw + BB*KKE);

    // 0) one-off weight transposes
    transpose_bf16_kernel<<<dim3(MHH/32, DD/32), 256, 0, stream>>>(Wm1, w1t, DD, MHH);
    transpose_bf16_kernel<<<dim3(DD/32, MHH/32), 256, 0, stream>>>(Wm2, w2t, MHH, DD);
    if (bigws){
        transpose_pad_w_kernel<<<dim3(PP/32, PP/32, EE), 256, 0, stream>>>(W1, w1tp, SS, THH);
        transpose_pad_w_kernel<<<dim3(PP/32, PP/32, EE), 256, 0, stream>>>(W2, w2tp, THH, SS);
    }
    // 1) LN1 -> nbf (bf16) + stats
    ln_bf16_kernel<<<MM, 256, 0, stream>>>(x, g1, be1, nbf, muv, rsigv);
    // 2) router (exact fp32) + aux
    meanvec_kernel<<<dim3(2, BB), 384, 0, stream>>>(x, muv, rsigv, g1, be1, mv);
    logits_kernel<<<BB, 64, 0, stream>>>(mv, Wg, bg, combine, probs, topi, topw);
    aux_kernel<<<1, 256, 0, stream>>>(combine, probs, out + N1);
    // 3) token mixing + residual -> x1 in d_out
    if (bigws){
        transpose_pad_n_kernel<<<dim3(DD/64, PP/64, BB), 256, 0, stream>>>(nbf, nTp);
        tok_gemm1_kernel<<<dim3(PP/128, DD/128, BB*KKE), 256, 0, stream>>>(nTp, w1tp, b1e, topi, htok);
        tok_gemm2_kernel<<<dim3(PP/128, DD/128, BB), 256, 0, stream>>>(htok, w2tp, b2e, topi, topw, x, out);
    } else {
        tokenmix2_kernel<<<dim3(DD/64, BB), 256, 0, stream>>>(nbf, x, W1, b1e, W2, b2e,
                                                              topi, topw, out);
    }
    // 4) LN2(x1) -> nbf
    ln_bf16_kernel<<<MM, 256, 0, stream>>>(out, g2, be2, nbf, muv, rsigv);
    // 5) channel MLP
    if (bigws){
        gemm_bt_kernel<DD, 0><<<dim3(MHH/128, MM/128), 256, 0, stream>>>(
            nbf, w1t, bm1, Hmlp, nullptr, MHH);
        gemm_bt_kernel<MHH, 1><<<dim3(DD/128, MM/128), 256, 0, stream>>>(
            Hmlp, w2t, bm2, nullptr, out, DD);
    } else {
        mlp_mfma_kernel<<<MM/32, 512, 0, stream>>>(nbf, w1t, bm1, w2t, bm2, out);
    }
}